// Round 6
// baseline (26.680 us; speedup 1.0000x reference)
//
#include <hip/hip_runtime.h>
#include <math.h>

#define NB 32
#define NT 128
#define KD 16

typedef float f32x4 __attribute__((ext_vector_type(4)));
typedef short bf16x8 __attribute__((ext_vector_type(8)));
typedef __fp16 f16x2 __attribute__((ext_vector_type(2)));
union U4B8 { uint4 u; bf16x8 h; };
union U4H8 { uint4 u; f16x2 h[4]; };

// LDS byte map (total 65280 < 64 KiB)
#define L_STATE 0        // [128][17] f32 = 8704 ; aliased by smP [64][64] f16 = 8192
#define L_Q     8704     // [16][68] f32 = 4352
#define L_PK    13056    // [128][68] f32 = 34816 ; aliased by X/H1/H2 after barrier
#define L_PV    47872    // [64][136] f16 = 17408
#define L_TOT   65280
#define L_X     13056    // [16][104] bf16 = 3328
#define L_H1    16384    // [16][264] bf16 = 8448
#define L_H2    24832    // [16][264] bf16 = 8448

__device__ __forceinline__ unsigned short bf16rne(float f) {
    unsigned u = __float_as_uint(f);
    return (unsigned short)((u + 0x7fffu + ((u >> 16) & 1u)) >> 16);
}
__device__ __forceinline__ unsigned cvt2bf(float a, float b) {
    unsigned r;
    asm("v_cvt_pk_bf16_f32 %0, %1, %2" : "=v"(r) : "v"(a), "v"(b));
    return r;   // lo16 = bf16(a), hi16 = bf16(b)
}
__device__ __forceinline__ void unpack8(uint4 u, float* f) {
    f[0] = __uint_as_float(u.x << 16); f[1] = __uint_as_float(u.x & 0xffff0000u);
    f[2] = __uint_as_float(u.y << 16); f[3] = __uint_as_float(u.y & 0xffff0000u);
    f[4] = __uint_as_float(u.z << 16); f[5] = __uint_as_float(u.z & 0xffff0000u);
    f[6] = __uint_as_float(u.w << 16); f[7] = __uint_as_float(u.w & 0xffff0000u);
}
__device__ __forceinline__ f16x2 pkmax(f16x2 a, f16x2 b) {
    f16x2 d;
    asm("v_pk_max_f16 %0, %1, %2" : "=v"(d) : "v"(a), "v"(b));
    return d;
}
#if __has_builtin(__builtin_amdgcn_fdot2)
#define FDOT2(a, b, c) __builtin_amdgcn_fdot2((a), (b), (c), false)
#else
#define FDOT2(a, b, c) ((c) + (float)(a)[0] * (float)(b)[0] + (float)(a)[1] * (float)(b)[1])
#endif

__global__ __launch_bounds__(1024, 4) void actor_kernel(
    const float* __restrict__ state, const float* __restrict__ eps,
    const float* __restrict__ Wq, const float* __restrict__ bq,
    const float* __restrict__ Wk, const float* __restrict__ bk,
    const float* __restrict__ Wv, const float* __restrict__ bv,
    const float* __restrict__ W1, const float* __restrict__ b1,
    const float* __restrict__ W2, const float* __restrict__ b2,
    const float* __restrict__ Wmu, const float* __restrict__ bmu,
    const float* __restrict__ Wls, const float* __restrict__ bls,
    float* __restrict__ out)
{
    __shared__ __align__(16) char sm[L_TOT];
    float* smS  = (float*)(sm + L_STATE);
    float* smQ  = (float*)(sm + L_Q);
    float* smPk = (float*)(sm + L_PK);

    const int tid = threadIdx.x, w = tid >> 6, lane = tid & 63;
    const int b = blockIdx.x >> 3, tile = blockIdx.x & 7;
    const int iloc = tile * 16 + w;                 // this wave's row in batch
    const int h = lane >> 4, s = lane & 15, h16 = h << 4;
    const int g = h, lr = s;                        // MFMA frag coords
    const int n1 = w * 16 + lr;                     // this wave's neuron column

    // ---- stage state[b] into LDS ([128][17] padded), prefetch X-tail ----
    if (tid < 512) {
        float4 v = ((const float4*)(state + (size_t)b * NT * KD))[tid];
        int r = tid >> 2, c = (tid & 3) * 4;
        float* dst = smS + r * 17 + c;
        dst[0] = v.x; dst[1] = v.y; dst[2] = v.z; dst[3] = v.w;
    }
    float stt = 0.f;
    if (tid < 256)
        stt = state[((size_t)b * NT + tile * 16 + (tid >> 4)) * KD + (tid & 15)];

    // per-lane projection weight columns (o = lane)
    float wqv[16], wkv[16], wvv[16];
    {
        const float4* q4 = (const float4*)(Wq + lane * KD);
        const float4* k4 = (const float4*)(Wk + lane * KD);
        const float4* v4 = (const float4*)(Wv + lane * KD);
        #pragma unroll
        for (int r4 = 0; r4 < 4; ++r4) {
            float4 a = q4[r4], c = k4[r4], d = v4[r4];
            wqv[r4*4+0]=a.x; wqv[r4*4+1]=a.y; wqv[r4*4+2]=a.z; wqv[r4*4+3]=a.w;
            wkv[r4*4+0]=c.x; wkv[r4*4+1]=c.y; wkv[r4*4+2]=c.z; wkv[r4*4+3]=c.w;
            wvv[r4*4+0]=d.x; wvv[r4*4+1]=d.y; wvv[r4*4+2]=d.z; wvv[r4*4+3]=d.w;
        }
    }
    __syncthreads();   // smS ready

    // ---- phase 1: Q (own row), Pk/Pv (8 j-rows per wave) ----
    {
        const float* sr = smS + iloc * 17;
        float aq = bq[lane];
        #pragma unroll
        for (int m = 0; m < 16; ++m) aq = fmaf(sr[m], wqv[m], aq);
        smQ[w * 68 + lane] = fmaxf(aq, 0.f) * 0.25f;   // 1/sqrt(16) folded
    }
    {
        float av[8];
        #pragma unroll
        for (int r = 0; r < 8; ++r) {
            const float* sr = smS + (w * 8 + r) * 17;
            float ak = 0.f, vv = 0.f;
            #pragma unroll
            for (int m = 0; m < 16; ++m) {
                ak = fmaf(sr[m], wkv[m], ak);
                vv = fmaf(sr[m], wvv[m], vv);
            }
            smPk[(w * 8 + r) * 68 + lane] = ak;
            av[r] = vv;
        }
        U4H8 pv;
        pv.h[0] = __builtin_amdgcn_cvt_pkrtz(av[0], av[1]);
        pv.h[1] = __builtin_amdgcn_cvt_pkrtz(av[2], av[3]);
        pv.h[2] = __builtin_amdgcn_cvt_pkrtz(av[4], av[5]);
        pv.h[3] = __builtin_amdgcn_cvt_pkrtz(av[6], av[7]);
        *(uint4*)(sm + L_PV + lane * 272 + w * 16) = pv.u;   // [o][j] f16
    }
    // W1 frags in-register (t = w), bf16
    uint4 w1f[3];
    #pragma unroll
    for (int ks = 0; ks < 3; ++ks) {
        int kb = ks * 32 + g * 8;
        if (kb < 80) {
            float4 lo = *(const float4*)(W1 + n1 * 80 + kb);
            float4 hi = *(const float4*)(W1 + n1 * 80 + kb + 4);
            w1f[ks].x = cvt2bf(lo.x, lo.y);
            w1f[ks].y = cvt2bf(lo.z, lo.w);
            w1f[ks].z = cvt2bf(hi.x, hi.y);
            w1f[ks].w = cvt2bf(hi.z, hi.w);
        } else {
            w1f[ks] = make_uint4(0, 0, 0, 0);
        }
    }
    __syncthreads();   // smQ / smPk / smPv ready

    // ---- phase 2: scores (f32) with relu-max identity ----
    float q[16], mbeff[16];
    float dotc = 0.f;
    {
        const float* qrow = smQ + w * 68 + h16;
        const float* pkI  = smPk + iloc * 68 + h16;
        const float4* bk4 = (const float4*)(bk + h16);
        #pragma unroll
        for (int q4 = 0; q4 < 4; ++q4) {
            float4 bb4 = bk4[q4];
            float bb[4] = {bb4.x, bb4.y, bb4.z, bb4.w};
            #pragma unroll
            for (int kk = 0; kk < 4; ++kk) {
                int k = q4 * 4 + kk;
                float qv = qrow[k], pk = pkI[k];
                q[k] = qv;
                mbeff[k] = pk - bb[kk];                  // -c
                dotc = fmaf(qv, bb[kk] - pk, dotc);      // sum q*c
            }
        }
    }
    float sc[8];
    #pragma unroll
    for (int jj = 0; jj < 8; ++jj) {
        const float* pk = smPk + (s + jj * 16) * 68 + h16;
        float a = dotc;
        #pragma unroll
        for (int k = 0; k < 16; ++k)
            a = fmaf(q[k], fmaxf(pk[k], mbeff[k]), a);
        sc[jj] = a;
    }
    // softmax across 16-lane head group (128 j)
    float mx = sc[0];
    #pragma unroll
    for (int jj = 1; jj < 8; ++jj) mx = fmaxf(mx, sc[jj]);
    #pragma unroll
    for (int off = 1; off < 16; off <<= 1) mx = fmaxf(mx, __shfl_xor(mx, off));
    float l = 0.f;
    #pragma unroll
    for (int jj = 0; jj < 8; ++jj) { sc[jj] = __expf(sc[jj] - mx); l += sc[jj]; }
    #pragma unroll
    for (int off = 1; off < 16; off <<= 1) l += __shfl_xor(l, off);
    const float rl = 1.0f / l;
    {
        __fp16* prow = (__fp16*)(sm + L_STATE) + (w * 4 + h) * 64;  // smP alias
        #pragma unroll
        for (int jj = 0; jj < 8; ++jj) prow[jj * 16 + s] = (__fp16)sc[jj];
    }
    asm volatile("s_waitcnt lgkmcnt(0)" ::: "memory");

    // ---- PV in packed f16: x = -mbv + rl * sum p~ * max(v, mbv) ----
    float xA;
    {
        const __fp16 pvi = *((const __fp16*)(sm + L_PV) + lane * 136 + iloc);
        const float mbvf = (float)pvi - bv[lane];
        const __fp16 mbvh = (__fp16)mbvf;
        const f16x2 mbv2 = {mbvh, mbvh};
        float acc = 0.f;
        #pragma unroll
        for (int u = 0; u < 16; ++u) {
            U4H8 v; v.u = *(const uint4*)(sm + L_PV + lane * 272 + u * 16);
            U4H8 p; p.u = *(const uint4*)(sm + L_STATE + (w * 4 + h) * 128 + u * 16);
            #pragma unroll
            for (int t = 0; t < 4; ++t)
                acc = FDOT2(p.h[t], pkmax(v.h[t], mbv2), acc);
        }
        xA = fmaf(rl, acc, -(float)mbvh);
    }
    __syncthreads();   // all smPk/smPv/smP reads done -> safe to alias

    // ---- X tile (bf16 [16][104], cols: 0..63 attn, 64..79 state, 80..95 zero) ----
    ((unsigned short*)(sm + L_X))[w * 104 + lane] = bf16rne(xA);
    if (tid < 256) {
        unsigned short* xr = (unsigned short*)(sm + L_X) + (tid >> 4) * 104;
        xr[64 + (tid & 15)] = bf16rne(stt);
        xr[80 + (tid & 15)] = 0;
    }
    // issue W2 loads now; consumed after L1 (latency hidden)
    float4 w2raw[16];
    #pragma unroll
    for (int ks = 0; ks < 8; ++ks) {
        w2raw[2 * ks]     = *(const float4*)(W2 + n1 * 256 + ks * 32 + g * 8);
        w2raw[2 * ks + 1] = *(const float4*)(W2 + n1 * 256 + ks * 32 + g * 8 + 4);
    }
    __syncthreads();

    // ---- layer 1 MFMA (K=96), wave w -> neurons w*16..w*16+15 ----
    {
        f32x4 a1 = {0.f, 0.f, 0.f, 0.f};
        #pragma unroll
        for (int ks = 0; ks < 3; ++ks) {
            U4B8 av; av.u = *(const uint4*)(sm + L_X + (lr * 104 + ks * 32 + g * 8) * 2);
            U4B8 bw; bw.u = w1f[ks];
            a1 = __builtin_amdgcn_mfma_f32_16x16x32_bf16(av.h, bw.h, a1, 0, 0, 0);
        }
        const float bn = b1[n1];
        #pragma unroll
        for (int qq = 0; qq < 4; ++qq)
            *((unsigned short*)(sm + L_H1) + (4 * g + qq) * 264 + n1) =
                bf16rne(fmaxf(a1[qq] + bn, 0.f));
    }
    __syncthreads();

    // ---- layer 2 MFMA (K=256) ----
    {
        f32x4 a2 = {0.f, 0.f, 0.f, 0.f};
        #pragma unroll
        for (int ks = 0; ks < 8; ++ks) {
            U4B8 av; av.u = *(const uint4*)(sm + L_H1 + (lr * 264 + ks * 32 + g * 8) * 2);
            U4B8 bw;
            bw.u.x = cvt2bf(w2raw[2*ks].x,   w2raw[2*ks].y);
            bw.u.y = cvt2bf(w2raw[2*ks].z,   w2raw[2*ks].w);
            bw.u.z = cvt2bf(w2raw[2*ks+1].x, w2raw[2*ks+1].y);
            bw.u.w = cvt2bf(w2raw[2*ks+1].z, w2raw[2*ks+1].w);
            a2 = __builtin_amdgcn_mfma_f32_16x16x32_bf16(av.h, bw.h, a2, 0, 0, 0);
        }
        const float bn = b2[n1];
        #pragma unroll
        for (int qq = 0; qq < 4; ++qq)
            *((unsigned short*)(sm + L_H2) + (4 * g + qq) * 264 + n1) =
                bf16rne(fmaxf(a2[qq] + bn, 0.f));
    }
    __syncthreads();

    // ---- heads + finalize (first 256 threads: row m, k-slice cc) ----
    if (tid < 256) {
        const int m = tid >> 4, cc = tid & 15;
        float hbuf[16];
        uint4 ha = *(const uint4*)(sm + L_H2 + (m * 264 + cc * 16) * 2);
        uint4 hb = *(const uint4*)(sm + L_H2 + (m * 264 + cc * 16 + 8) * 2);
        unpack8(ha, hbuf); unpack8(hb, hbuf + 8);
        float d0 = 0.f, d1 = 0.f, d2 = 0.f, d3 = 0.f;
        #pragma unroll
        for (int kk = 0; kk < 16; ++kk) {
            int k = cc * 16 + kk;
            float hv = hbuf[kk];
            d0 = fmaf(hv, Wmu[k], d0);
            d1 = fmaf(hv, Wmu[256 + k], d1);
            d2 = fmaf(hv, Wls[k], d2);
            d3 = fmaf(hv, Wls[256 + k], d3);
        }
        #pragma unroll
        for (int off = 1; off < 16; off <<= 1) {
            d0 += __shfl_xor(d0, off);
            d1 += __shfl_xor(d1, off);
            d2 += __shfl_xor(d2, off);
            d3 += __shfl_xor(d3, off);
        }
        if (cc == 0) {
            const int row = b * NT + tile * 16 + m;
            float mu0 = tanhf(d0 + bmu[0]);
            float mu1 = tanhf(d1 + bmu[1]);
            float t2  = tanhf(d2 + bls[0]);
            float t3  = tanhf(d3 + bls[1]);
            float ls0 = -20.f + 11.f * (t2 + 1.f);
            float ls1 = -20.f + 11.f * (t3 + 1.f);
            float e0 = eps[row * 2], e1 = eps[row * 2 + 1];
            float z0 = mu0 + __expf(ls0) * e0;
            float z1 = mu1 + __expf(ls1) * e1;
            float a0 = tanhf(z0), a1 = tanhf(z1);
            out[row * 2]     = a0;
            out[row * 2 + 1] = a1;
            float lp = -0.5f * e0 * e0 - ls0 - 0.91893853320467274f - __logf(1.f - a0 * a0 + 1e-7f)
                     + -0.5f * e1 * e1 - ls1 - 0.91893853320467274f - __logf(1.f - a1 * a1 + 1e-7f);
            out[NB * NT * 2 + row] = lp;
        }
    }
}

extern "C" void kernel_launch(void* const* d_in, const int* in_sizes, int n_in,
                              void* d_out, int out_size, void* d_ws, size_t ws_size,
                              hipStream_t stream) {
    const float* state = (const float*)d_in[0];
    const float* eps   = (const float*)d_in[1];
    const float* Wq    = (const float*)d_in[2];
    const float* bq    = (const float*)d_in[3];
    const float* Wk    = (const float*)d_in[4];
    const float* bk    = (const float*)d_in[5];
    const float* Wv    = (const float*)d_in[6];
    const float* bv    = (const float*)d_in[7];
    const float* W1    = (const float*)d_in[8];
    const float* b1    = (const float*)d_in[9];
    const float* W2    = (const float*)d_in[10];
    const float* b2    = (const float*)d_in[11];
    const float* Wmu   = (const float*)d_in[12];
    const float* bmu   = (const float*)d_in[13];
    const float* Wls   = (const float*)d_in[14];
    const float* bls   = (const float*)d_in[15];
    float* out = (float*)d_out;
    (void)d_ws; (void)ws_size;

    actor_kernel<<<NB * 8, 1024, 0, stream>>>(
        state, eps, Wq, bq, Wk, bk, Wv, bv, W1, b1, W2, b2,
        Wmu, bmu, Wls, bls, out);
}